// Round 9
// baseline (1095.748 us; speedup 1.0000x reference)
//
#include <hip/hip_runtime.h>

#define BB 256
#define TT 2048
#define HH 32
#define G4 128   // 4*H
#define XB 32    // (b,t) positions per xproj block

// Fast sigmoid/tanh via v_exp_f32 + v_rcp_f32 (~1 ulp each).
__device__ __forceinline__ float fsig(float x) {
  return __builtin_amdgcn_rcpf(1.0f + __expf(-x));
}
__device__ __forceinline__ float ftanh(float x) {
  // 1 - 2/(exp(2x)+1); saturates correctly at +/-inf
  return 1.0f - 2.0f * __builtin_amdgcn_rcpf(__expf(2.0f * x) + 1.0f);
}

// Loop-carried empty asm: pins values in arch VGPRs so the compiler cannot
// rematerialize (re-load) them inside the loop (round-1 evidence: VGPR_Count
// was 44 < 64 resident weights => per-step re-loads on the serial path).
#define KEEP8(a)                                                          \
  asm(""                                                                  \
      : "+v"((a)[0]), "+v"((a)[1]), "+v"((a)[2]), "+v"((a)[3]),           \
        "+v"((a)[4]), "+v"((a)[5]), "+v"((a)[6]), "+v"((a)[7]))

// ---------------------------------------------------------------------------
// Kernel 1: x_gates[bt][j] = float4(i,f,g,o) preactivations from W_ih.x+biases
// 256 threads, 32 (b,t) positions per block; W_ih transposed+padded in LDS.
// One thread owns one (bt, j): stores one float4 -> 1 KB contiguous per wave.
// ---------------------------------------------------------------------------
__global__ __launch_bounds__(256) void xproj2(
    const float* __restrict__ x, const float* __restrict__ W_ih,
    const float* __restrict__ b_ih, const float* __restrict__ b_hh,
    float4* __restrict__ xg) {
  __shared__ float wT[HH][G4 + 1];  // wT[k][r]; pad -> conflict-free
  __shared__ float xs[XB * HH];     // 32 x-rows (4 KB)
  __shared__ float bias[G4];
  const int tid = threadIdx.x;

#pragma unroll
  for (int i = tid; i < G4 * HH; i += 256) wT[i & 31][i >> 5] = W_ih[i];
  if (tid < G4) bias[tid] = b_ih[tid] + b_hh[tid];
  const size_t bt0 = (size_t)blockIdx.x * XB;
  ((float4*)xs)[tid] = ((const float4*)(x + bt0 * HH))[tid];
  __syncthreads();

  const int j = tid & 31, btl = tid >> 5;
  const float b0 = bias[j], b1 = bias[HH + j], b2 = bias[2 * HH + j],
              b3 = bias[3 * HH + j];
#pragma unroll
  for (int q = 0; q < 4; ++q) {
    const int p = btl + 8 * q;
    const float* xr = xs + p * HH;
    float a0 = b0, a1 = b1, a2 = b2, a3 = b3;
#pragma unroll
    for (int k = 0; k < HH; ++k) {
      const float xv = xr[k];
      a0 = fmaf(wT[k][j], xv, a0);
      a1 = fmaf(wT[k][HH + j], xv, a1);
      a2 = fmaf(wT[k][2 * HH + j], xv, a2);
      a3 = fmaf(wT[k][3 * HH + j], xv, a3);
    }
    xg[(bt0 + p) * HH + j] = make_float4(a0, a1, a2, a3);
  }
}

// ---------------------------------------------------------------------------
// One LSTM step. Lanes 0-31 own gates (i,f) for j=lane&31, lanes 32-63 own
// (g,o); full K=32 dots with W_hh rows in VGPRs and h broadcast via
// readlane->SGPR. Halves exchange pre-activations with 2x shfl_xor(32)
// (validated wiring from round 1).
// ---------------------------------------------------------------------------
#define STEP(xi, tt)                                                        \
  {                                                                         \
    float hk[HH];                                                           \
    _Pragma("unroll") for (int k = 0; k < HH; ++k) hk[k] =                  \
        __uint_as_float(__builtin_amdgcn_readlane(__float_as_uint(h), k));  \
    float a0 = hf ? (xi).z : (xi).x;                                        \
    float a1 = hf ? (xi).w : (xi).y;                                        \
    float s0 = 0.f, s1 = 0.f;                                               \
    _Pragma("unroll") for (int k = 0; k < 16; ++k) {                        \
      a0 = fmaf(whh0[k], hk[k], a0);                                        \
      a1 = fmaf(whh1[k], hk[k], a1);                                        \
      s0 = fmaf(whh0[k + 16], hk[k + 16], s0);                              \
      s1 = fmaf(whh1[k + 16], hk[k + 16], s1);                              \
    }                                                                       \
    a0 += s0;                                                               \
    a1 += s1;                                                               \
    const float o0 = __shfl_xor(a0, 32);                                    \
    const float o1 = __shfl_xor(a1, 32);                                    \
    const float ai = hf ? o0 : a0;                                          \
    const float af = hf ? o1 : a1;                                          \
    const float ag = hf ? a0 : o0;                                          \
    const float ao = hf ? a1 : o1;                                          \
    const float gi = fsig(ai), gf = fsig(af), go = fsig(ao);                \
    const float gg = ftanh(ag);                                             \
    c = fmaf(gf, c, gi * gg);                                               \
    h = go * ftanh(c);                                                      \
    if (!hf) outp[(tt)*HH + j] = fminf(fmaxf(h, -1.f), 1.f);                \
  }

__global__ __launch_bounds__(64, 1) void lstm_rec2(
    const float4* __restrict__ xg, const float* __restrict__ W_hh,
    float* __restrict__ out) {
  const int b = blockIdx.x;
  const int lane = threadIdx.x, j = lane & 31, hf = lane >> 5;
  const int r0 = (hf * 2 + 0) * HH + j;  // i (hf=0) / g (hf=1)
  const int r1 = (hf * 2 + 1) * HH + j;  // f (hf=0) / o (hf=1)

  float whh0[HH], whh1[HH];
  {
    const float4* w0 = (const float4*)(W_hh + (size_t)r0 * HH);
    const float4* w1 = (const float4*)(W_hh + (size_t)r1 * HH);
#pragma unroll
    for (int k4 = 0; k4 < HH / 4; ++k4) {
      float4 a = w0[k4], d = w1[k4];
      whh0[k4 * 4 + 0] = a.x; whh0[k4 * 4 + 1] = a.y;
      whh0[k4 * 4 + 2] = a.z; whh0[k4 * 4 + 3] = a.w;
      whh1[k4 * 4 + 0] = d.x; whh1[k4 * 4 + 1] = d.y;
      whh1[k4 * 4 + 2] = d.z; whh1[k4 * 4 + 3] = d.w;
    }
  }

  float h = 0.f, c = 0.f;
  const size_t base = (size_t)b * TT;
  const float4* src = xg + base * HH + j;  // stride HH float4 per timestep
  float* outp = out + base * HH;

  float4 c0 = src[0], c1 = src[HH], c2 = src[2 * HH], c3 = src[3 * HH];
  for (int t = 0; t < TT; t += 4) {
    // Pin weights in VGPRs across the loop (see KEEP8 comment).
    KEEP8(whh0); KEEP8(whh0 + 8); KEEP8(whh0 + 16); KEEP8(whh0 + 24);
    KEEP8(whh1); KEEP8(whh1 + 8); KEEP8(whh1 + 16); KEEP8(whh1 + 24);

    const int tp = (t + 4 < TT) ? t + 4 : TT - 4;  // 4-deep prefetch
    float4 n0 = src[(size_t)(tp + 0) * HH];
    float4 n1 = src[(size_t)(tp + 1) * HH];
    float4 n2 = src[(size_t)(tp + 2) * HH];
    float4 n3 = src[(size_t)(tp + 3) * HH];
    STEP(c0, t);
    STEP(c1, t + 1);
    STEP(c2, t + 2);
    STEP(c3, t + 3);
    c0 = n0; c1 = n1; c2 = n2; c3 = n3;
  }
}

// ---------------------------------------------------------------------------
// Fallback (no workspace): fused input projection. (Round-1 evidence says the
// workspace path runs; this is insurance only.)
// ---------------------------------------------------------------------------
__global__ __launch_bounds__(64, 1) void lstm_rec_fused(
    const float* __restrict__ x, const float* __restrict__ W_ih,
    const float* __restrict__ W_hh, const float* __restrict__ b_ih,
    const float* __restrict__ b_hh, float* __restrict__ out) {
  const int b = blockIdx.x;
  const int lane = threadIdx.x, j = lane & 31, hf = lane >> 5;
  const int r0 = (hf * 2 + 0) * HH + j;
  const int r1 = (hf * 2 + 1) * HH + j;

  float whh0[HH], whh1[HH], wih0[HH], wih1[HH];
#pragma unroll
  for (int k4 = 0; k4 < HH / 4; ++k4) {
    float4 a = ((const float4*)(W_hh + (size_t)r0 * HH))[k4];
    float4 d = ((const float4*)(W_hh + (size_t)r1 * HH))[k4];
    float4 e = ((const float4*)(W_ih + (size_t)r0 * HH))[k4];
    float4 f = ((const float4*)(W_ih + (size_t)r1 * HH))[k4];
    whh0[k4 * 4 + 0] = a.x; whh0[k4 * 4 + 1] = a.y;
    whh0[k4 * 4 + 2] = a.z; whh0[k4 * 4 + 3] = a.w;
    whh1[k4 * 4 + 0] = d.x; whh1[k4 * 4 + 1] = d.y;
    whh1[k4 * 4 + 2] = d.z; whh1[k4 * 4 + 3] = d.w;
    wih0[k4 * 4 + 0] = e.x; wih0[k4 * 4 + 1] = e.y;
    wih0[k4 * 4 + 2] = e.z; wih0[k4 * 4 + 3] = e.w;
    wih1[k4 * 4 + 0] = f.x; wih1[k4 * 4 + 1] = f.y;
    wih1[k4 * 4 + 2] = f.z; wih1[k4 * 4 + 3] = f.w;
  }
  const float bias0 = b_ih[r0] + b_hh[r0];
  const float bias1 = b_ih[r1] + b_hh[r1];

  float h = 0.f, c = 0.f;
  const size_t base = (size_t)b * TT;
  float* outp = out + base * HH;
  float xv_n = x[base * HH + j];

  for (int t = 0; t < TT; ++t) {
    KEEP8(whh0); KEEP8(whh0 + 8); KEEP8(whh0 + 16); KEEP8(whh0 + 24);
    KEEP8(whh1); KEEP8(whh1 + 8); KEEP8(whh1 + 16); KEEP8(whh1 + 24);
    KEEP8(wih0); KEEP8(wih0 + 8); KEEP8(wih0 + 16); KEEP8(wih0 + 24);
    KEEP8(wih1); KEEP8(wih1 + 8); KEEP8(wih1 + 16); KEEP8(wih1 + 24);

    const float xvc = xv_n;
    const int tn = (t + 1 < TT) ? t + 1 : TT - 1;
    xv_n = x[(base + tn) * HH + j];

    float hk[HH], xk[HH];
#pragma unroll
    for (int k = 0; k < HH; ++k) {
      hk[k] = __uint_as_float(__builtin_amdgcn_readlane(__float_as_uint(h), k));
      xk[k] =
          __uint_as_float(__builtin_amdgcn_readlane(__float_as_uint(xvc), k));
    }
    float a0 = bias0, a1 = bias1;
#pragma unroll
    for (int k = 0; k < HH; ++k) {
      a0 = fmaf(wih0[k], xk[k], a0);
      a1 = fmaf(wih1[k], xk[k], a1);
      a0 = fmaf(whh0[k], hk[k], a0);
      a1 = fmaf(whh1[k], hk[k], a1);
    }
    const float o0 = __shfl_xor(a0, 32);
    const float o1 = __shfl_xor(a1, 32);
    const float ai = hf ? o0 : a0;
    const float af = hf ? o1 : a1;
    const float ag = hf ? a0 : o0;
    const float ao = hf ? a1 : o1;
    const float gi = fsig(ai), gf = fsig(af), go = fsig(ao);
    const float gg = ftanh(ag);
    c = fmaf(gf, c, gi * gg);
    h = go * ftanh(c);
    if (!hf) outp[t * HH + j] = fminf(fmaxf(h, -1.f), 1.f);
  }
}

extern "C" void kernel_launch(void* const* d_in, const int* in_sizes, int n_in,
                              void* d_out, int out_size, void* d_ws,
                              size_t ws_size, hipStream_t stream) {
  const float* x    = (const float*)d_in[0];
  const float* W_ih = (const float*)d_in[1];
  const float* W_hh = (const float*)d_in[2];
  const float* b_ih = (const float*)d_in[3];
  const float* b_hh = (const float*)d_in[4];
  float* out = (float*)d_out;

  const size_t need = (size_t)BB * TT * G4 * sizeof(float);  // 256 MiB
  if (ws_size >= need) {
    float4* xg = (float4*)d_ws;
    xproj2<<<BB * TT / XB, 256, 0, stream>>>(x, W_ih, b_ih, b_hh, xg);
    lstm_rec2<<<BB, 64, 0, stream>>>(xg, W_hh, out);
  } else {
    lstm_rec_fused<<<BB, 64, 0, stream>>>(x, W_ih, W_hh, b_ih, b_hh, out);
  }
}